// Round 4
// baseline (981.456 us; speedup 1.0000x reference)
//
#include <hip/hip_runtime.h>
#include <hip/hip_bf16.h>

#define S_LEN 2048
#define NHQ 32
#define NHKV 8
#define DH 128
#define KTILE 32
#define KS_PITCH 136   // ushorts; row stride 272B
#define VT_PITCH 40    // ushorts; row stride 80B = 20 dwords -> b128 R/W uniform banks
#define PS_PITCH 40

typedef float f32x4 __attribute__((ext_vector_type(4)));
typedef short bf16x8 __attribute__((ext_vector_type(8)));
typedef float float4_t __attribute__((ext_vector_type(4)));

__device__ __forceinline__ unsigned short f2bf(float f) {
  union { __hip_bfloat16 h; unsigned short u; } c;
  c.h = __float2bfloat16(f);
  return c.u;
}

__device__ __forceinline__ bf16x8 pack8(float4_t a, float4_t b) {
  bf16x8 f;
  f[0] = (short)f2bf(a[0]); f[1] = (short)f2bf(a[1]);
  f[2] = (short)f2bf(a[2]); f[3] = (short)f2bf(a[3]);
  f[4] = (short)f2bf(b[0]); f[5] = (short)f2bf(b[1]);
  f[6] = (short)f2bf(b[2]); f[7] = (short)f2bf(b[3]);
  return f;
}

__global__ __launch_bounds__(256, 2) void attn_fwd(
    const float* __restrict__ Q, const float* __restrict__ K,
    const float* __restrict__ V, float* __restrict__ O) {
  __shared__ unsigned short Ks[2][KTILE * KS_PITCH];  // double-buffered K tile
  __shared__ unsigned short Vt[2][DH * VT_PITCH];     // double-buffered V^T tile
  __shared__ unsigned short Ps[4][32 * PS_PITCH];     // per-wave P

  const int bid = blockIdx.x;
  const int kvh = bid & 7;            // XCD-locality: one KV-head per XCD
  const int qt = 63 - (bid >> 3);     // heavy q-tiles dispatched first
  const int q0 = qt * 32;
  const int tid = threadIdx.x;
  const int wid = tid >> 6;
  const int lane = tid & 63;
  const int l15 = lane & 15;
  const int l4 = lane >> 4;
  const int h = kvh * 4 + wid;        // wave = one q-head of this GQA group

  // scale * log2(e), folded into Q at pack time (softmax in exp2 domain)
  const float kscale = 0.08838834764831845f * 1.44269504088896340f;

  // ---- hoist Q (pre-scaled): A-frag row=l&15, k=(l>>4)*8+j ----
  bf16x8 qf[2][4];
#pragma unroll
  for (int qr = 0; qr < 2; ++qr) {
    const float* qp = Q + ((size_t)(q0 + qr * 16 + l15) * NHQ + h) * DH;
#pragma unroll
    for (int dc = 0; dc < 4; ++dc) {
      float4_t a = *(const float4_t*)(qp + dc * 32 + l4 * 8);
      float4_t b = *(const float4_t*)(qp + dc * 32 + l4 * 8 + 4);
      a *= kscale;
      b *= kscale;
      qf[qr][dc] = pack8(a, b);
    }
  }

  f32x4 o[2][8];
#pragma unroll
  for (int qr = 0; qr < 2; ++qr)
#pragma unroll
    for (int dt = 0; dt < 8; ++dt) o[qr][dt] = (f32x4){0.f, 0.f, 0.f, 0.f};
  float mrow[8] = {-1e30f, -1e30f, -1e30f, -1e30f, -1e30f, -1e30f, -1e30f, -1e30f};
  float lrow[8] = {0.f, 0.f, 0.f, 0.f, 0.f, 0.f, 0.f, 0.f};

  // V staging role: thread owns one d (0..127), half the k-range (16 keys)
  const int vd = tid & 127;
  const int vkh = tid >> 7;
  const float* vbase = V + ((size_t)(vkh * 16) * NHKV + kvh) * DH + vd;

  // ---- staging helpers: load globals -> regs; cvt+write regs -> LDS buf ----
  auto load_tile = [&](int kv0, float4_t (&ka)[2][2], float (&vv)[16]) {
#pragma unroll
    for (int i = 0; i < 2; ++i) {
      int c = tid + i * 256;
      int row = c >> 4;
      int col = (c & 15) * 8;
      const float* kp = K + ((size_t)(kv0 + row) * NHKV + kvh) * DH + col;
      ka[i][0] = *(const float4_t*)kp;
      ka[i][1] = *(const float4_t*)(kp + 4);
    }
    const float* vp = vbase + (size_t)kv0 * (NHKV * DH);
#pragma unroll
    for (int k = 0; k < 16; ++k) vv[k] = vp[(size_t)k * (NHKV * DH)];
  };
  auto store_tile = [&](int buf, float4_t (&ka)[2][2], float (&vv)[16]) {
#pragma unroll
    for (int i = 0; i < 2; ++i) {
      int c = tid + i * 256;
      int row = c >> 4;
      int col = (c & 15) * 8;
      *(bf16x8*)&Ks[buf][row * KS_PITCH + col] = pack8(ka[i][0], ka[i][1]);
    }
    bf16x8 a, b;
#pragma unroll
    for (int j = 0; j < 8; ++j) {
      a[j] = (short)f2bf(vv[j]);
      b[j] = (short)f2bf(vv[8 + j]);
    }
    *(bf16x8*)&Vt[buf][vd * VT_PITCH + vkh * 16] = a;
    *(bf16x8*)&Vt[buf][vd * VT_PITCH + vkh * 16 + 8] = b;
  };

  float4_t ka[2][2];
  float vv[16];

  // prologue: stage tile 0 into buf 0
  load_tile(0, ka, vv);
  store_tile(0, ka, vv);
  __syncthreads();

  const int ntile = qt + 1;  // causal: keys 0 .. q0+31
  for (int t = 0; t < ntile; ++t) {
    const int cur = t & 1;
    const bool pf = (t + 1 < ntile);
    if (pf) load_tile((t + 1) * KTILE, ka, vv);  // issue early: hides under MFMA

    // ---- S = Q K^T on buf[cur] ----
    const unsigned short* KsC = Ks[cur];
    f32x4 s[2][2];
    s[0][0] = (f32x4){0.f, 0.f, 0.f, 0.f}; s[0][1] = (f32x4){0.f, 0.f, 0.f, 0.f};
    s[1][0] = (f32x4){0.f, 0.f, 0.f, 0.f}; s[1][1] = (f32x4){0.f, 0.f, 0.f, 0.f};
#pragma unroll
    for (int dc = 0; dc < 4; ++dc) {
      bf16x8 k0 = *(const bf16x8*)&KsC[l15 * KS_PITCH + dc * 32 + l4 * 8];
      bf16x8 k1 = *(const bf16x8*)&KsC[(16 + l15) * KS_PITCH + dc * 32 + l4 * 8];
      s[0][0] = __builtin_amdgcn_mfma_f32_16x16x32_bf16(qf[0][dc], k0, s[0][0], 0, 0, 0);
      s[0][1] = __builtin_amdgcn_mfma_f32_16x16x32_bf16(qf[0][dc], k1, s[0][1], 0, 0, 0);
      s[1][0] = __builtin_amdgcn_mfma_f32_16x16x32_bf16(qf[1][dc], k0, s[1][0], 0, 0, 0);
      s[1][1] = __builtin_amdgcn_mfma_f32_16x16x32_bf16(qf[1][dc], k1, s[1][1], 0, 0, 0);
    }

    // ---- softmax pass 1: mask + row max ----
    const bool needmask = (t == qt);
    float tv0[8], tv1[8], mxr[8];
#pragma unroll
    for (int qr = 0; qr < 2; ++qr) {
#pragma unroll
      for (int r = 0; r < 4; ++r) {
        const int ri = qr * 4 + r;
        float t0 = s[qr][0][r];
        float t1 = s[qr][1][r];
        if (needmask) {
          int qg = qr * 16 + l4 * 4 + r;  // C/D layout: row=(lane>>4)*4+reg
          if (l15 > qg) t0 = -1e30f;
          if (16 + l15 > qg) t1 = -1e30f;
        }
        float mx = fmaxf(t0, t1);
        mx = fmaxf(mx, __shfl_xor(mx, 1, 16));
        mx = fmaxf(mx, __shfl_xor(mx, 2, 16));
        mx = fmaxf(mx, __shfl_xor(mx, 4, 16));
        mx = fmaxf(mx, __shfl_xor(mx, 8, 16));
        tv0[ri] = t0; tv1[ri] = t1; mxr[ri] = mx;
      }
    }

    // ---- defer-max: wave-uniform skip of the O-rescale (THR=8 in exp2 dom) ----
    bool small = true;
#pragma unroll
    for (int ri = 0; ri < 8; ++ri) small &= (mxr[ri] <= mrow[ri] + 8.0f);
    const bool skiprs = __all((int)small);

    if (skiprs) {
#pragma unroll
      for (int ri = 0; ri < 8; ++ri) {
        float p0 = __builtin_amdgcn_exp2f(tv0[ri] - mrow[ri]);
        float p1 = __builtin_amdgcn_exp2f(tv1[ri] - mrow[ri]);
        lrow[ri] += p0 + p1;
        unsigned short* pw = &Ps[wid][((ri >> 2) * 16 + l4 * 4 + (ri & 3)) * PS_PITCH];
        pw[l15] = f2bf(p0);
        pw[16 + l15] = f2bf(p1);
      }
    } else {
#pragma unroll
      for (int ri = 0; ri < 8; ++ri) {
        float mn = fmaxf(mrow[ri], mxr[ri]);
        float al = __builtin_amdgcn_exp2f(mrow[ri] - mn);
        float p0 = __builtin_amdgcn_exp2f(tv0[ri] - mn);
        float p1 = __builtin_amdgcn_exp2f(tv1[ri] - mn);
        mrow[ri] = mn;
        lrow[ri] = lrow[ri] * al + p0 + p1;
        const int qr = ri >> 2, r = ri & 3;
#pragma unroll
        for (int dt = 0; dt < 8; ++dt) o[qr][dt][r] *= al;
        unsigned short* pw = &Ps[wid][(qr * 16 + l4 * 4 + r) * PS_PITCH];
        pw[l15] = f2bf(p0);
        pw[16 + l15] = f2bf(p1);
      }
    }

    // ---- O += P V on buf[cur] ----
    const unsigned short* VtC = Vt[cur];
    bf16x8 pa0 = *(const bf16x8*)&Ps[wid][l15 * PS_PITCH + l4 * 8];
    bf16x8 pa1 = *(const bf16x8*)&Ps[wid][(16 + l15) * PS_PITCH + l4 * 8];
#pragma unroll
    for (int dt = 0; dt < 8; ++dt) {
      bf16x8 bv = *(const bf16x8*)&VtC[(dt * 16 + l15) * VT_PITCH + l4 * 8];
      o[0][dt] = __builtin_amdgcn_mfma_f32_16x16x32_bf16(pa0, bv, o[0][dt], 0, 0, 0);
      o[1][dt] = __builtin_amdgcn_mfma_f32_16x16x32_bf16(pa1, bv, o[1][dt], 0, 0, 0);
    }

    // ---- write next tile into the other buffer; single barrier per tile ----
    if (pf) store_tile(cur ^ 1, ka, vv);
    __syncthreads();
  }

  // ---- epilogue: reduce row sums, normalize, store fp32 ----
#pragma unroll
  for (int qr = 0; qr < 2; ++qr) {
#pragma unroll
    for (int r = 0; r < 4; ++r) {
      const int ri = qr * 4 + r;
      float ssum = lrow[ri];
      ssum += __shfl_xor(ssum, 1, 16);
      ssum += __shfl_xor(ssum, 2, 16);
      ssum += __shfl_xor(ssum, 4, 16);
      ssum += __shfl_xor(ssum, 8, 16);
      float inv = 1.0f / ssum;
      int qg = q0 + qr * 16 + l4 * 4 + r;
      float* op = O + ((size_t)qg * NHQ + h) * DH;
#pragma unroll
      for (int dt = 0; dt < 8; ++dt) op[dt * 16 + l15] = o[qr][dt][r] * inv;
    }
  }
}

extern "C" void kernel_launch(void* const* d_in, const int* in_sizes, int n_in,
                              void* d_out, int out_size, void* d_ws, size_t ws_size,
                              hipStream_t stream) {
  const float* Q = (const float*)d_in[0];
  const float* K = (const float*)d_in[1];
  const float* V = (const float*)d_in[2];
  float* O = (float*)d_out;
  attn_fwd<<<dim3((S_LEN / 32) * NHKV), dim3(256), 0, stream>>>(Q, K, V, O);
}

// Round 5
// 220.787 us; speedup vs baseline: 4.4453x; 4.4453x over previous
//
#include <hip/hip_runtime.h>
#include <hip/hip_bf16.h>

#define S_LEN 2048
#define NHQ 32
#define NHKV 8
#define DH 128
#define KTILE 32
#define KS_PITCH 136   // ushorts; row stride 272B
#define VT_PITCH 40    // ushorts; row stride 80B = 20 dwords -> b128 R/W uniform banks
#define PS_PITCH 40
#define KV_STRIDE ((size_t)NHKV * DH)

typedef float f32x4 __attribute__((ext_vector_type(4)));
typedef short bf16x8 __attribute__((ext_vector_type(8)));
typedef float float4_t __attribute__((ext_vector_type(4)));

__device__ __forceinline__ unsigned short f2bf(float f) {
  union { __hip_bfloat16 h; unsigned short u; } c;
  c.h = __float2bfloat16(f);
  return c.u;
}

__device__ __forceinline__ bf16x8 pack8(float4_t a, float4_t b) {
  bf16x8 f;
  f[0] = (short)f2bf(a[0]); f[1] = (short)f2bf(a[1]);
  f[2] = (short)f2bf(a[2]); f[3] = (short)f2bf(a[3]);
  f[4] = (short)f2bf(b[0]); f[5] = (short)f2bf(b[1]);
  f[6] = (short)f2bf(b[2]); f[7] = (short)f2bf(b[3]);
  return f;
}

__global__ __launch_bounds__(256, 2) void attn_fwd(
    const float* __restrict__ Q, const float* __restrict__ K,
    const float* __restrict__ V, float* __restrict__ O) {
  __shared__ unsigned short Ks[2][KTILE * KS_PITCH];  // double-buffered K tile
  __shared__ unsigned short Vt[2][DH * VT_PITCH];     // double-buffered V^T tile
  __shared__ unsigned short Ps[4][32 * PS_PITCH];     // per-wave P

  const int bid = blockIdx.x;
  const int kvh = bid & 7;            // XCD-locality: one KV-head per XCD
  const int qt = 63 - (bid >> 3);     // heavy q-tiles dispatched first
  const int q0 = qt * 32;
  const int tid = threadIdx.x;
  const int wid = tid >> 6;
  const int lane = tid & 63;
  const int l15 = lane & 15;
  const int l4 = lane >> 4;
  const int h = kvh * 4 + wid;        // wave = one q-head of this GQA group

  // scale * log2(e), folded into Q at pack time (softmax in exp2 domain)
  const float kscale = 0.08838834764831845f * 1.44269504088896340f;

  // ---- hoist Q (pre-scaled): A-frag row=l&15, k=(l>>4)*8+j ----
  bf16x8 qf[2][4];
#pragma unroll
  for (int qr = 0; qr < 2; ++qr) {
    const float* qp = Q + ((size_t)(q0 + qr * 16 + l15) * NHQ + h) * DH;
#pragma unroll
    for (int dc = 0; dc < 4; ++dc) {
      float4_t a = *(const float4_t*)(qp + dc * 32 + l4 * 8);
      float4_t b = *(const float4_t*)(qp + dc * 32 + l4 * 8 + 4);
      a *= kscale;
      b *= kscale;
      qf[qr][dc] = pack8(a, b);
    }
  }

  f32x4 o[2][8];
#pragma unroll
  for (int qr = 0; qr < 2; ++qr)
#pragma unroll
    for (int dt = 0; dt < 8; ++dt) o[qr][dt] = (f32x4){0.f, 0.f, 0.f, 0.f};
  float mrow[8] = {-1e30f, -1e30f, -1e30f, -1e30f, -1e30f, -1e30f, -1e30f, -1e30f};
  float lrow[8] = {0.f, 0.f, 0.f, 0.f, 0.f, 0.f, 0.f, 0.f};

  // staging roles
  const int krow = tid >> 4;          // 0..15 (K rows krow and krow+16)
  const int kcol = (tid & 15) * 8;    // 0..120
  const float* kbase = K + ((size_t)krow * NHKV + kvh) * DH + kcol;
  const int vd = tid & 127;           // thread owns one d
  const int vkh = tid >> 7;           // half the k-range (16 keys)
  const float* vbase = V + ((size_t)(vkh * 16) * NHKV + kvh) * DH + vd;

  // in-flight tile: individually NAMED registers (no arrays -> no scratch)
  float4_t kra0, kra1, krb0, krb1;    // K row krow (a) and krow+16 (b)
  float4_t vr0, vr1, vr2, vr3;        // 16 V floats, d=vd, k = vkh*16 + 0..15

  auto load_tile = [&](int kv0) {
    const float* kp = kbase + (size_t)kv0 * KV_STRIDE;
    kra0 = *(const float4_t*)kp;
    kra1 = *(const float4_t*)(kp + 4);
    const float* kp2 = kp + 16 * KV_STRIDE;
    krb0 = *(const float4_t*)kp2;
    krb1 = *(const float4_t*)(kp2 + 4);
    const float* vp = vbase + (size_t)kv0 * KV_STRIDE;
    vr0 = (float4_t){vp[0 * KV_STRIDE], vp[1 * KV_STRIDE], vp[2 * KV_STRIDE], vp[3 * KV_STRIDE]};
    vr1 = (float4_t){vp[4 * KV_STRIDE], vp[5 * KV_STRIDE], vp[6 * KV_STRIDE], vp[7 * KV_STRIDE]};
    vr2 = (float4_t){vp[8 * KV_STRIDE], vp[9 * KV_STRIDE], vp[10 * KV_STRIDE], vp[11 * KV_STRIDE]};
    vr3 = (float4_t){vp[12 * KV_STRIDE], vp[13 * KV_STRIDE], vp[14 * KV_STRIDE], vp[15 * KV_STRIDE]};
  };
  auto store_tile = [&](int buf) {
    *(bf16x8*)&Ks[buf][krow * KS_PITCH + kcol] = pack8(kra0, kra1);
    *(bf16x8*)&Ks[buf][(krow + 16) * KS_PITCH + kcol] = pack8(krb0, krb1);
    *(bf16x8*)&Vt[buf][vd * VT_PITCH + vkh * 16] = pack8(vr0, vr1);
    *(bf16x8*)&Vt[buf][vd * VT_PITCH + vkh * 16 + 8] = pack8(vr2, vr3);
  };

  // prologue: stage tile 0 into buf 0
  load_tile(0);
  store_tile(0);
  __syncthreads();

  const int ntile = qt + 1;  // causal: keys 0 .. q0+31
  for (int t = 0; t < ntile; ++t) {
    const int cur = t & 1;
    const bool pf = (t + 1 < ntile);
    if (pf) load_tile((t + 1) * KTILE);  // issue early: hides under MFMA

    // ---- S = Q K^T on buf[cur] ----
    const unsigned short* KsC = Ks[cur];
    f32x4 s[2][2];
    s[0][0] = (f32x4){0.f, 0.f, 0.f, 0.f}; s[0][1] = (f32x4){0.f, 0.f, 0.f, 0.f};
    s[1][0] = (f32x4){0.f, 0.f, 0.f, 0.f}; s[1][1] = (f32x4){0.f, 0.f, 0.f, 0.f};
#pragma unroll
    for (int dc = 0; dc < 4; ++dc) {
      bf16x8 k0 = *(const bf16x8*)&KsC[l15 * KS_PITCH + dc * 32 + l4 * 8];
      bf16x8 k1 = *(const bf16x8*)&KsC[(16 + l15) * KS_PITCH + dc * 32 + l4 * 8];
      s[0][0] = __builtin_amdgcn_mfma_f32_16x16x32_bf16(qf[0][dc], k0, s[0][0], 0, 0, 0);
      s[0][1] = __builtin_amdgcn_mfma_f32_16x16x32_bf16(qf[0][dc], k1, s[0][1], 0, 0, 0);
      s[1][0] = __builtin_amdgcn_mfma_f32_16x16x32_bf16(qf[1][dc], k0, s[1][0], 0, 0, 0);
      s[1][1] = __builtin_amdgcn_mfma_f32_16x16x32_bf16(qf[1][dc], k1, s[1][1], 0, 0, 0);
    }

    // ---- softmax pass 1: mask + row max ----
    const bool needmask = (t == qt);
    float tv0[8], tv1[8], mxr[8];
#pragma unroll
    for (int qr = 0; qr < 2; ++qr) {
#pragma unroll
      for (int r = 0; r < 4; ++r) {
        const int ri = qr * 4 + r;
        float t0 = s[qr][0][r];
        float t1 = s[qr][1][r];
        if (needmask) {
          int qg = qr * 16 + l4 * 4 + r;  // C/D layout: row=(lane>>4)*4+reg
          if (l15 > qg) t0 = -1e30f;
          if (16 + l15 > qg) t1 = -1e30f;
        }
        float mx = fmaxf(t0, t1);
        mx = fmaxf(mx, __shfl_xor(mx, 1, 16));
        mx = fmaxf(mx, __shfl_xor(mx, 2, 16));
        mx = fmaxf(mx, __shfl_xor(mx, 4, 16));
        mx = fmaxf(mx, __shfl_xor(mx, 8, 16));
        tv0[ri] = t0; tv1[ri] = t1; mxr[ri] = mx;
      }
    }

    // ---- defer-max: wave-uniform skip of the O-rescale (THR=8 in exp2 dom) ----
    bool small = true;
#pragma unroll
    for (int ri = 0; ri < 8; ++ri) small &= (mxr[ri] <= mrow[ri] + 8.0f);
    const bool skiprs = __all((int)small);

    if (skiprs) {
#pragma unroll
      for (int ri = 0; ri < 8; ++ri) {
        float p0 = __builtin_amdgcn_exp2f(tv0[ri] - mrow[ri]);
        float p1 = __builtin_amdgcn_exp2f(tv1[ri] - mrow[ri]);
        lrow[ri] += p0 + p1;
        unsigned short* pw = &Ps[wid][((ri >> 2) * 16 + l4 * 4 + (ri & 3)) * PS_PITCH];
        pw[l15] = f2bf(p0);
        pw[16 + l15] = f2bf(p1);
      }
    } else {
#pragma unroll
      for (int ri = 0; ri < 8; ++ri) {
        float mn = fmaxf(mrow[ri], mxr[ri]);
        float al = __builtin_amdgcn_exp2f(mrow[ri] - mn);
        float p0 = __builtin_amdgcn_exp2f(tv0[ri] - mn);
        float p1 = __builtin_amdgcn_exp2f(tv1[ri] - mn);
        mrow[ri] = mn;
        lrow[ri] = lrow[ri] * al + p0 + p1;
        const int qr = ri >> 2, r = ri & 3;
#pragma unroll
        for (int dt = 0; dt < 8; ++dt) o[qr][dt][r] *= al;
        unsigned short* pw = &Ps[wid][(qr * 16 + l4 * 4 + r) * PS_PITCH];
        pw[l15] = f2bf(p0);
        pw[16 + l15] = f2bf(p1);
      }
    }

    // ---- O += P V on buf[cur] ----
    const unsigned short* VtC = Vt[cur];
    bf16x8 pa0 = *(const bf16x8*)&Ps[wid][l15 * PS_PITCH + l4 * 8];
    bf16x8 pa1 = *(const bf16x8*)&Ps[wid][(16 + l15) * PS_PITCH + l4 * 8];
#pragma unroll
    for (int dt = 0; dt < 8; ++dt) {
      bf16x8 bv = *(const bf16x8*)&VtC[(dt * 16 + l15) * VT_PITCH + l4 * 8];
      o[0][dt] = __builtin_amdgcn_mfma_f32_16x16x32_bf16(pa0, bv, o[0][dt], 0, 0, 0);
      o[1][dt] = __builtin_amdgcn_mfma_f32_16x16x32_bf16(pa1, bv, o[1][dt], 0, 0, 0);
    }

    // ---- write next tile into the other buffer; single barrier per tile ----
    if (pf) store_tile(cur ^ 1);
    __syncthreads();
  }

  // ---- epilogue: reduce row sums, normalize, store fp32 ----
#pragma unroll
  for (int qr = 0; qr < 2; ++qr) {
#pragma unroll
    for (int r = 0; r < 4; ++r) {
      const int ri = qr * 4 + r;
      float ssum = lrow[ri];
      ssum += __shfl_xor(ssum, 1, 16);
      ssum += __shfl_xor(ssum, 2, 16);
      ssum += __shfl_xor(ssum, 4, 16);
      ssum += __shfl_xor(ssum, 8, 16);
      float inv = 1.0f / ssum;
      int qg = q0 + qr * 16 + l4 * 4 + r;
      float* op = O + ((size_t)qg * NHQ + h) * DH;
#pragma unroll
      for (int dt = 0; dt < 8; ++dt) op[dt * 16 + l15] = o[qr][dt][r] * inv;
    }
  }
}

extern "C" void kernel_launch(void* const* d_in, const int* in_sizes, int n_in,
                              void* d_out, int out_size, void* d_ws, size_t ws_size,
                              hipStream_t stream) {
  const float* Q = (const float*)d_in[0];
  const float* K = (const float*)d_in[1];
  const float* V = (const float*)d_in[2];
  float* O = (float*)d_out;
  attn_fwd<<<dim3((S_LEN / 32) * NHKV), dim3(256), 0, stream>>>(Q, K, V, O);
}

// Round 6
// 217.910 us; speedup vs baseline: 4.5039x; 1.0132x over previous
//
#include <hip/hip_runtime.h>
#include <hip/hip_bf16.h>

#define S_LEN 2048
#define NHQ 32
#define NHKV 8
#define DH 128
#define KTILE 32
#define KS_PITCH 136   // ushorts; row stride 272B
#define VT_PITCH 40    // ushorts; row stride 80B = 20 dwords -> b128 R/W uniform banks
#define PS_PITCH 40
#define KV_STRIDE ((size_t)NHKV * DH)

typedef float f32x4 __attribute__((ext_vector_type(4)));
typedef short bf16x8 __attribute__((ext_vector_type(8)));
typedef float float4_t __attribute__((ext_vector_type(4)));

__device__ __forceinline__ unsigned short f2bf(float f) {
  union { __hip_bfloat16 h; unsigned short u; } c;
  c.h = __float2bfloat16(f);
  return c.u;
}

__device__ __forceinline__ bf16x8 pack8(float4_t a, float4_t b) {
  bf16x8 f;
  f[0] = (short)f2bf(a[0]); f[1] = (short)f2bf(a[1]);
  f[2] = (short)f2bf(a[2]); f[3] = (short)f2bf(a[3]);
  f[4] = (short)f2bf(b[0]); f[5] = (short)f2bf(b[1]);
  f[6] = (short)f2bf(b[2]); f[7] = (short)f2bf(b[3]);
  return f;
}

__global__ __launch_bounds__(256, 2) void attn_fwd(
    const float* __restrict__ Q, const float* __restrict__ K,
    const float* __restrict__ V, float* __restrict__ O) {
  __shared__ unsigned short Ks[2][KTILE * KS_PITCH];  // double-buffered K tile
  __shared__ unsigned short Vt[2][DH * VT_PITCH];     // double-buffered V^T tile
  __shared__ unsigned short Ps[4][32 * PS_PITCH];     // per-wave P

  const int bid = blockIdx.x;
  const int kvh = bid & 7;            // XCD-locality: one KV-head per XCD
  // Complementary pairing: CU_j gets one block from each half -> qt sum = 63
  // (65 tile-units per CU, eliminates the triangular-causal tail).
  const int qt = (bid < 256) ? (63 - (bid >> 3)) : ((bid - 256) >> 3);
  const int q0 = qt * 32;
  const int tid = threadIdx.x;
  const int wid = tid >> 6;
  const int lane = tid & 63;
  const int l15 = lane & 15;
  const int l4 = lane >> 4;
  const int h = kvh * 4 + wid;        // wave = one q-head of this GQA group

  // scale * log2(e), folded into Q at pack time (softmax in exp2 domain)
  const float kscale = 0.08838834764831845f * 1.44269504088896340f;

  // ---- hoist Q (pre-scaled): A-frag row=l&15, k=(l>>4)*8+j ----
  bf16x8 qf[2][4];
#pragma unroll
  for (int qr = 0; qr < 2; ++qr) {
    const float* qp = Q + ((size_t)(q0 + qr * 16 + l15) * NHQ + h) * DH;
#pragma unroll
    for (int dc = 0; dc < 4; ++dc) {
      float4_t a = *(const float4_t*)(qp + dc * 32 + l4 * 8);
      float4_t b = *(const float4_t*)(qp + dc * 32 + l4 * 8 + 4);
      a *= kscale;
      b *= kscale;
      qf[qr][dc] = pack8(a, b);
    }
  }

  f32x4 o[2][8];
#pragma unroll
  for (int qr = 0; qr < 2; ++qr)
#pragma unroll
    for (int dt = 0; dt < 8; ++dt) o[qr][dt] = (f32x4){0.f, 0.f, 0.f, 0.f};
  float mrow[8] = {-1e30f, -1e30f, -1e30f, -1e30f, -1e30f, -1e30f, -1e30f, -1e30f};
  float lrow[8] = {0.f, 0.f, 0.f, 0.f, 0.f, 0.f, 0.f, 0.f};

  // staging roles
  const int krow = tid >> 4;          // 0..15 (K rows krow and krow+16)
  const int kcol = (tid & 15) * 8;    // 0..120
  const float* kbase = K + ((size_t)krow * NHKV + kvh) * DH + kcol;
  const int vd = tid & 127;           // thread owns one d
  const int vkh = tid >> 7;           // half the k-range (16 keys)
  const float* vbase = V + ((size_t)(vkh * 16) * NHKV + kvh) * DH + vd;

  // in-flight tile: individually NAMED registers (no arrays -> no scratch)
  float4_t kra0, kra1, krb0, krb1;    // K row krow (a) and krow+16 (b)
  float4_t vr0, vr1, vr2, vr3;        // 16 V floats, d=vd, k = vkh*16 + 0..15

  auto load_tile = [&](int kv0) {
    const float* kp = kbase + (size_t)kv0 * KV_STRIDE;
    kra0 = *(const float4_t*)kp;
    kra1 = *(const float4_t*)(kp + 4);
    const float* kp2 = kp + 16 * KV_STRIDE;
    krb0 = *(const float4_t*)kp2;
    krb1 = *(const float4_t*)(kp2 + 4);
    const float* vp = vbase + (size_t)kv0 * KV_STRIDE;
    vr0 = (float4_t){vp[0 * KV_STRIDE], vp[1 * KV_STRIDE], vp[2 * KV_STRIDE], vp[3 * KV_STRIDE]};
    vr1 = (float4_t){vp[4 * KV_STRIDE], vp[5 * KV_STRIDE], vp[6 * KV_STRIDE], vp[7 * KV_STRIDE]};
    vr2 = (float4_t){vp[8 * KV_STRIDE], vp[9 * KV_STRIDE], vp[10 * KV_STRIDE], vp[11 * KV_STRIDE]};
    vr3 = (float4_t){vp[12 * KV_STRIDE], vp[13 * KV_STRIDE], vp[14 * KV_STRIDE], vp[15 * KV_STRIDE]};
  };
  auto store_tile = [&](int buf) {
    *(bf16x8*)&Ks[buf][krow * KS_PITCH + kcol] = pack8(kra0, kra1);
    *(bf16x8*)&Ks[buf][(krow + 16) * KS_PITCH + kcol] = pack8(krb0, krb1);
    *(bf16x8*)&Vt[buf][vd * VT_PITCH + vkh * 16] = pack8(vr0, vr1);
    *(bf16x8*)&Vt[buf][vd * VT_PITCH + vkh * 16 + 8] = pack8(vr2, vr3);
  };

  // prologue: stage tile 0 into buf 0
  load_tile(0);
  store_tile(0);
  __syncthreads();

  const int ntile = qt + 1;  // causal: keys 0 .. q0+31
  for (int t = 0; t < ntile; ++t) {
    const int cur = t & 1;
    const bool pf = (t + 1 < ntile);
    if (pf) load_tile((t + 1) * KTILE);  // issue early: hides under MFMA

    // ---- S = Q K^T on buf[cur] ----
    const unsigned short* KsC = Ks[cur];
    f32x4 s[2][2];
    s[0][0] = (f32x4){0.f, 0.f, 0.f, 0.f}; s[0][1] = (f32x4){0.f, 0.f, 0.f, 0.f};
    s[1][0] = (f32x4){0.f, 0.f, 0.f, 0.f}; s[1][1] = (f32x4){0.f, 0.f, 0.f, 0.f};
#pragma unroll
    for (int dc = 0; dc < 4; ++dc) {
      bf16x8 k0 = *(const bf16x8*)&KsC[l15 * KS_PITCH + dc * 32 + l4 * 8];
      bf16x8 k1 = *(const bf16x8*)&KsC[(16 + l15) * KS_PITCH + dc * 32 + l4 * 8];
      s[0][0] = __builtin_amdgcn_mfma_f32_16x16x32_bf16(qf[0][dc], k0, s[0][0], 0, 0, 0);
      s[0][1] = __builtin_amdgcn_mfma_f32_16x16x32_bf16(qf[0][dc], k1, s[0][1], 0, 0, 0);
      s[1][0] = __builtin_amdgcn_mfma_f32_16x16x32_bf16(qf[1][dc], k0, s[1][0], 0, 0, 0);
      s[1][1] = __builtin_amdgcn_mfma_f32_16x16x32_bf16(qf[1][dc], k1, s[1][1], 0, 0, 0);
    }

    // ---- softmax pass 1: mask + row max ----
    const bool needmask = (t == qt);
    float tv0[8], tv1[8], mxr[8];
#pragma unroll
    for (int qr = 0; qr < 2; ++qr) {
#pragma unroll
      for (int r = 0; r < 4; ++r) {
        const int ri = qr * 4 + r;
        float t0 = s[qr][0][r];
        float t1 = s[qr][1][r];
        if (needmask) {
          int qg = qr * 16 + l4 * 4 + r;  // C/D layout: row=(lane>>4)*4+reg
          if (l15 > qg) t0 = -1e30f;
          if (16 + l15 > qg) t1 = -1e30f;
        }
        float mx = fmaxf(t0, t1);
        mx = fmaxf(mx, __shfl_xor(mx, 1, 16));
        mx = fmaxf(mx, __shfl_xor(mx, 2, 16));
        mx = fmaxf(mx, __shfl_xor(mx, 4, 16));
        mx = fmaxf(mx, __shfl_xor(mx, 8, 16));
        tv0[ri] = t0; tv1[ri] = t1; mxr[ri] = mx;
      }
    }

    // ---- defer-max: wave-uniform skip of the O-rescale (THR=8 in exp2 dom) ----
    bool small = true;
#pragma unroll
    for (int ri = 0; ri < 8; ++ri) small &= (mxr[ri] <= mrow[ri] + 8.0f);
    const bool skiprs = __all((int)small);

    if (skiprs) {
#pragma unroll
      for (int ri = 0; ri < 8; ++ri) {
        float p0 = __builtin_amdgcn_exp2f(tv0[ri] - mrow[ri]);
        float p1 = __builtin_amdgcn_exp2f(tv1[ri] - mrow[ri]);
        lrow[ri] += p0 + p1;
        unsigned short* pw = &Ps[wid][((ri >> 2) * 16 + l4 * 4 + (ri & 3)) * PS_PITCH];
        pw[l15] = f2bf(p0);
        pw[16 + l15] = f2bf(p1);
      }
    } else {
#pragma unroll
      for (int ri = 0; ri < 8; ++ri) {
        float mn = fmaxf(mrow[ri], mxr[ri]);
        float al = __builtin_amdgcn_exp2f(mrow[ri] - mn);
        float p0 = __builtin_amdgcn_exp2f(tv0[ri] - mn);
        float p1 = __builtin_amdgcn_exp2f(tv1[ri] - mn);
        mrow[ri] = mn;
        lrow[ri] = lrow[ri] * al + p0 + p1;
        const int qr = ri >> 2, r = ri & 3;
#pragma unroll
        for (int dt = 0; dt < 8; ++dt) o[qr][dt][r] *= al;
        unsigned short* pw = &Ps[wid][(qr * 16 + l4 * 4 + r) * PS_PITCH];
        pw[l15] = f2bf(p0);
        pw[16 + l15] = f2bf(p1);
      }
    }

    // ---- O += P V on buf[cur] ----
    const unsigned short* VtC = Vt[cur];
    bf16x8 pa0 = *(const bf16x8*)&Ps[wid][l15 * PS_PITCH + l4 * 8];
    bf16x8 pa1 = *(const bf16x8*)&Ps[wid][(16 + l15) * PS_PITCH + l4 * 8];
#pragma unroll
    for (int dt = 0; dt < 8; ++dt) {
      bf16x8 bv = *(const bf16x8*)&VtC[(dt * 16 + l15) * VT_PITCH + l4 * 8];
      o[0][dt] = __builtin_amdgcn_mfma_f32_16x16x32_bf16(pa0, bv, o[0][dt], 0, 0, 0);
      o[1][dt] = __builtin_amdgcn_mfma_f32_16x16x32_bf16(pa1, bv, o[1][dt], 0, 0, 0);
    }

    // ---- write next tile into the other buffer; single barrier per tile ----
    if (pf) store_tile(cur ^ 1);
    __syncthreads();
  }

  // ---- epilogue: reduce row sums, normalize, store fp32 ----
#pragma unroll
  for (int qr = 0; qr < 2; ++qr) {
#pragma unroll
    for (int r = 0; r < 4; ++r) {
      const int ri = qr * 4 + r;
      float ssum = lrow[ri];
      ssum += __shfl_xor(ssum, 1, 16);
      ssum += __shfl_xor(ssum, 2, 16);
      ssum += __shfl_xor(ssum, 4, 16);
      ssum += __shfl_xor(ssum, 8, 16);
      float inv = 1.0f / ssum;
      int qg = q0 + qr * 16 + l4 * 4 + r;
      float* op = O + ((size_t)qg * NHQ + h) * DH;
#pragma unroll
      for (int dt = 0; dt < 8; ++dt) op[dt * 16 + l15] = o[qr][dt][r] * inv;
    }
  }
}

extern "C" void kernel_launch(void* const* d_in, const int* in_sizes, int n_in,
                              void* d_out, int out_size, void* d_ws, size_t ws_size,
                              hipStream_t stream) {
  const float* Q = (const float*)d_in[0];
  const float* K = (const float*)d_in[1];
  const float* V = (const float*)d_in[2];
  float* O = (float*)d_out;
  attn_fwd<<<dim3((S_LEN / 32) * NHKV), dim3(256), 0, stream>>>(Q, K, V, O);
}